// Round 8
// baseline (256.164 us; speedup 1.0000x reference)
//
#include <hip/hip_runtime.h>

#define B_N 256
#define B_C 256
#define MID 128
#define NELEM (B_N * B_C)
#define CK 64           // K-chunk width (cols)
#define NC 4            // number of chunks

typedef float f32x4 __attribute__((ext_vector_type(4)));
typedef __bf16 bf16x8 __attribute__((ext_vector_type(8)));
typedef short short8 __attribute__((ext_vector_type(8)));

// native casts -> v_cvt_pk_bf16_f32 (RTNE)
__device__ __forceinline__ short8 cvt8(float4 a, float4 b) {
  union { unsigned short us[8]; short8 v; } P;
  P.us[0] = __builtin_bit_cast(unsigned short, (__bf16)a.x);
  P.us[1] = __builtin_bit_cast(unsigned short, (__bf16)a.y);
  P.us[2] = __builtin_bit_cast(unsigned short, (__bf16)a.z);
  P.us[3] = __builtin_bit_cast(unsigned short, (__bf16)a.w);
  P.us[4] = __builtin_bit_cast(unsigned short, (__bf16)b.x);
  P.us[5] = __builtin_bit_cast(unsigned short, (__bf16)b.y);
  P.us[6] = __builtin_bit_cast(unsigned short, (__bf16)b.z);
  P.us[7] = __builtin_bit_cast(unsigned short, (__bf16)b.w);
  return P.v;
}

// One block per batch, 512 threads (8 waves), ~37 KB LDS -> 2+ blocks/CU.
// K-loop stages 256x64 bf16 chunks (32 KB, single-buffered); phase overlap
// across co-resident blocks comes from TLP, not manual pipelining.
// Output phase re-reads x from global (L3-resident) -> no full-X LDS needed.
__global__ __launch_bounds__(512, 4) void spat_attn(
    const float* __restrict__ x, const float* __restrict__ kern,
    const float* __restrict__ bias, float* __restrict__ out)
{
  __shared__ __align__(16) unsigned short Xc[B_N * CK];  // 32 KB swizzled bf16 chunk
  __shared__ float smid[B_N];
  __shared__ float r2s[B_N];
  __shared__ float vb[B_N];
  __shared__ float wlog[B_N];
  __shared__ float wexp[B_N];

  const int tid = threadIdx.x;
  const int b = blockIdx.x;
  const float* __restrict__ xb = x + (size_t)b * NELEM;

  // MFMA lane geometry (16x16x32, verified C/D layout)
  const int w  = tid >> 6;
  const int l  = tid & 63;
  const int lr = l & 15;
  const int g  = l >> 4;
  const int sw = lr & 7;
  const int rb0 = 32 * w + lr;
  const int rb1 = rb0 + 16;

  f32x4 acc[16][2];
  #pragma unroll
  for (int t = 0; t < 16; ++t) {
    acc[t][0] = {0.f, 0.f, 0.f, 0.f};
    acc[t][1] = {0.f, 0.f, 0.f, 0.f};
  }

  // ---- K-loop: stage chunk c (f32->bf16->LDS), then MFMA over it ----
  for (int c = 0; c < NC; ++c) {
    if (c > 0) __syncthreads();   // previous chunk fully consumed
    // stage: 4 sweeps x 8 elems/thread; within chunk e = row*64 + col
    #pragma unroll
    for (int s = 0; s < 4; ++s) {
      const int e = s * 4096 + tid * 8;
      const int row = e >> 6;
      const int col = e & 63;
      const float* p = xb + row * B_C + c * CK + col;
      const float4 f0 = *reinterpret_cast<const float4*>(p);
      const float4 f1 = *reinterpret_cast<const float4*>(p + 4);
      const int q = col >> 3;
      *reinterpret_cast<short8*>(&Xc[(row << 6) + ((q ^ (row & 7)) << 3)]) =
          cvt8(f0, f1);
    }
    __syncthreads();
    // MFMA: 2 k-steps of 32 within this 64-col chunk
    #pragma unroll
    for (int kkl = 0; kkl < 2; ++kkl) {
      const int qs = (((4 * kkl + g) ^ sw) << 3);
      const bf16x8 bf0 = __builtin_bit_cast(bf16x8,
          *reinterpret_cast<const short8*>(&Xc[(rb0 << 6) + qs]));
      const bf16x8 bf1 = __builtin_bit_cast(bf16x8,
          *reinterpret_cast<const short8*>(&Xc[(rb1 << 6) + qs]));
      #pragma unroll
      for (int t = 0; t < 16; ++t) {
        const bf16x8 af = __builtin_bit_cast(bf16x8,
            *reinterpret_cast<const short8*>(&Xc[((16 * t + lr) << 6) + qs]));
        acc[t][0] = __builtin_amdgcn_mfma_f32_16x16x32_bf16(af, bf0, acc[t][0], 0, 0, 0);
        acc[t][1] = __builtin_amdgcn_mfma_f32_16x16x32_bf16(af, bf1, acc[t][1], 0, 0, 0);
      }
    }
  }

  // ---- reductions (R1-verified): r2 per column == per row by symmetry ----
  float rp0 = 0.f, rp1 = 0.f;
  #pragma unroll
  for (int t = 0; t < 16; ++t) {
    #pragma unroll
    for (int r = 0; r < 4; ++r) {
      rp0 += acc[t][0][r] * acc[t][0][r];
      rp1 += acc[t][1][r] * acc[t][1][r];
    }
  }
  rp0 += __shfl_xor(rp0, 16); rp0 += __shfl_xor(rp0, 32);
  rp1 += __shfl_xor(rp1, 16); rp1 += __shfl_xor(rp1, 32);
  if (l < 16) {
    r2s[32 * w + l]      = rp0;
    r2s[32 * w + 16 + l] = rp1;
    smid[32 * w + l]      = acc[8][0][0];   // row MID: tile 8, reg 0, g==0
    smid[32 * w + 16 + l] = acc[8][1][0];
  }
  __syncthreads();

  if (tid < B_N) {
    const float rinvm = rsqrtf(fmaxf(r2s[MID], 1e-12f));
    vb[tid] = smid[tid] * rinvm * kern[tid];
  }
  __syncthreads();

  float up0 = 0.f, up1 = 0.f;
  #pragma unroll
  for (int t = 0; t < 16; ++t) {
    #pragma unroll
    for (int r = 0; r < 4; ++r) {
      const float vv = vb[16 * t + 4 * g + r];
      up0 += acc[t][0][r] * vv;
      up1 += acc[t][1][r] * vv;
    }
  }
  up0 += __shfl_xor(up0, 16); up0 += __shfl_xor(up0, 32);
  up1 += __shfl_xor(up1, 16); up1 += __shfl_xor(up1, 32);
  if (l < 16) {
    const int n0 = 32 * w + l, n1 = n0 + 16;
    wlog[n0] = up0 * rsqrtf(fmaxf(r2s[n0], 1e-12f)) + bias[n0];
    wlog[n1] = up1 * rsqrtf(fmaxf(r2s[n1], 1e-12f)) + bias[n1];
  }
  __syncthreads();

  // softmax over the 256 logits (wave 0)
  if (tid < 64) {
    const float a0 = wlog[tid], a1 = wlog[tid + 64], a2 = wlog[tid + 128], a3 = wlog[tid + 192];
    float mx = fmaxf(fmaxf(a0, a1), fmaxf(a2, a3));
    #pragma unroll
    for (int off = 32; off >= 1; off >>= 1) mx = fmaxf(mx, __shfl_xor(mx, off));
    const float e0 = __expf(a0 - mx), e1 = __expf(a1 - mx), e2 = __expf(a2 - mx), e3 = __expf(a3 - mx);
    float s = e0 + e1 + e2 + e3;
    #pragma unroll
    for (int off = 32; off >= 1; off >>= 1) s += __shfl_xor(s, off);
    const float inv = 1.0f / s;
    wexp[tid] = e0 * inv; wexp[tid + 64] = e1 * inv;
    wexp[tid + 128] = e2 * inv; wexp[tid + 192] = e3 * inv;
  }
  __syncthreads();

  // ---- output: re-read x from global (L3-resident), out = p[row] * x ----
  float* __restrict__ ob = out + (size_t)b * NELEM;
  #pragma unroll 4
  for (int i = 0; i < 16; ++i) {
    const int e8 = i * 4096 + tid * 8;
    const float wt = wexp[e8 >> 8];
    const float4 f0 = *reinterpret_cast<const float4*>(xb + e8);
    const float4 f1 = *reinterpret_cast<const float4*>(xb + e8 + 4);
    f32x4 o0, o1;
    o0[0] = f0.x * wt; o0[1] = f0.y * wt; o0[2] = f0.z * wt; o0[3] = f0.w * wt;
    o1[0] = f1.x * wt; o1[1] = f1.y * wt; o1[2] = f1.z * wt; o1[3] = f1.w * wt;
    *reinterpret_cast<f32x4*>(ob + e8)     = o0;
    *reinterpret_cast<f32x4*>(ob + e8 + 4) = o1;
  }
}

extern "C" void kernel_launch(void* const* d_in, const int* in_sizes, int n_in,
                              void* d_out, int out_size, void* d_ws, size_t ws_size,
                              hipStream_t stream) {
  const float* x    = (const float*)d_in[0];
  const float* kern = (const float*)d_in[1];
  const float* bias = (const float*)d_in[2];
  float* out = (float*)d_out;
  const int nb = in_sizes[0] / NELEM;          // 512 batches
  spat_attn<<<dim3(nb), dim3(512), 0, stream>>>(x, kern, bias, out);
}

// Round 9
// 92.690 us; speedup vs baseline: 2.7637x; 2.7637x over previous
//
#include <hip/hip_runtime.h>

#define B_N 256
#define B_C 256
#define MID 128
#define NELEM (B_N * B_C)

typedef float f32x4 __attribute__((ext_vector_type(4)));
typedef __bf16 bf16x8 __attribute__((ext_vector_type(8)));
typedef short short8 __attribute__((ext_vector_type(8)));

// native casts -> v_cvt_pk_bf16_f32 (RTNE)
__device__ __forceinline__ short8 cvt8(float4 a, float4 b) {
  union { unsigned short us[8]; short8 v; } P;
  P.us[0] = __builtin_bit_cast(unsigned short, (__bf16)a.x);
  P.us[1] = __builtin_bit_cast(unsigned short, (__bf16)a.y);
  P.us[2] = __builtin_bit_cast(unsigned short, (__bf16)a.z);
  P.us[3] = __builtin_bit_cast(unsigned short, (__bf16)a.w);
  P.us[4] = __builtin_bit_cast(unsigned short, (__bf16)b.x);
  P.us[5] = __builtin_bit_cast(unsigned short, (__bf16)b.y);
  P.us[6] = __builtin_bit_cast(unsigned short, (__bf16)b.z);
  P.us[7] = __builtin_bit_cast(unsigned short, (__bf16)b.w);
  return P.v;
}

// ---------------- Kernel 1: R1 phases 1-2, write wexp[b][n] to d_ws --------
// One block per batch, 512 threads. X staged bf16+swizzled in LDS, sim via
// MFMA (stays in VGPRs/AGPRs), reductions by symmetry, softmax -> 256 floats.
__global__ __launch_bounds__(512, 1) void spat_attn_w(
    const float* __restrict__ x, const float* __restrict__ kern,
    const float* __restrict__ bias, float* __restrict__ wexp_g)
{
  __shared__ __align__(16) unsigned short Xs[NELEM];  // 128 KB swizzled bf16
  __shared__ float smid[B_N];
  __shared__ float r2s[B_N];
  __shared__ float vb[B_N];
  __shared__ float wlog[B_N];
  __shared__ float wexp[B_N];

  const int b = blockIdx.x;
  const int tid = threadIdx.x;
  const float* __restrict__ xb = x + (size_t)b * NELEM;

  // Phase 1: load + convert + swizzled LDS store
  #pragma unroll 4
  for (int i = 0; i < 16; ++i) {
    const int e8 = i * 4096 + tid * 8;
    const float4 f0 = *reinterpret_cast<const float4*>(xb + e8);
    const float4 f1 = *reinterpret_cast<const float4*>(xb + e8 + 4);
    const int r = e8 >> 8;
    const int q = (e8 >> 3) & 31;
    *reinterpret_cast<short8*>(&Xs[(r << 8) + ((q ^ (r & 7)) << 3)]) = cvt8(f0, f1);
  }
  __syncthreads();

  // Phase 2: sim + reductions
  const int w  = tid >> 6;
  const int l  = tid & 63;
  const int lr = l & 15;
  const int g  = l >> 4;
  const int sw = lr & 7;

  f32x4 acc[16][2];
  #pragma unroll
  for (int t = 0; t < 16; ++t) {
    acc[t][0] = {0.f, 0.f, 0.f, 0.f};
    acc[t][1] = {0.f, 0.f, 0.f, 0.f};
  }

  const int rb0 = 32 * w + lr;
  const int rb1 = rb0 + 16;
  #pragma unroll
  for (int kk = 0; kk < 8; ++kk) {
    const int qs = (((4 * kk + g) ^ sw) << 3);
    const bf16x8 bf0 = __builtin_bit_cast(bf16x8,
        *reinterpret_cast<const short8*>(&Xs[(rb0 << 8) + qs]));
    const bf16x8 bf1 = __builtin_bit_cast(bf16x8,
        *reinterpret_cast<const short8*>(&Xs[(rb1 << 8) + qs]));
    #pragma unroll
    for (int t = 0; t < 16; ++t) {
      const bf16x8 af = __builtin_bit_cast(bf16x8,
          *reinterpret_cast<const short8*>(&Xs[((16 * t + lr) << 8) + qs]));
      acc[t][0] = __builtin_amdgcn_mfma_f32_16x16x32_bf16(af, bf0, acc[t][0], 0, 0, 0);
      acc[t][1] = __builtin_amdgcn_mfma_f32_16x16x32_bf16(af, bf1, acc[t][1], 0, 0, 0);
    }
  }

  float rp0 = 0.f, rp1 = 0.f;
  #pragma unroll
  for (int t = 0; t < 16; ++t) {
    #pragma unroll
    for (int r = 0; r < 4; ++r) {
      rp0 += acc[t][0][r] * acc[t][0][r];
      rp1 += acc[t][1][r] * acc[t][1][r];
    }
  }
  rp0 += __shfl_xor(rp0, 16); rp0 += __shfl_xor(rp0, 32);
  rp1 += __shfl_xor(rp1, 16); rp1 += __shfl_xor(rp1, 32);
  if (l < 16) {
    r2s[32 * w + l]      = rp0;
    r2s[32 * w + 16 + l] = rp1;
    smid[32 * w + l]      = acc[8][0][0];   // row MID: tile 8, reg 0, g==0
    smid[32 * w + 16 + l] = acc[8][1][0];
  }
  __syncthreads();

  if (tid < B_N) {
    const float rinvm = rsqrtf(fmaxf(r2s[MID], 1e-12f));
    vb[tid] = smid[tid] * rinvm * kern[tid];
  }
  __syncthreads();

  float up0 = 0.f, up1 = 0.f;
  #pragma unroll
  for (int t = 0; t < 16; ++t) {
    #pragma unroll
    for (int r = 0; r < 4; ++r) {
      const float vv = vb[16 * t + 4 * g + r];
      up0 += acc[t][0][r] * vv;
      up1 += acc[t][1][r] * vv;
    }
  }
  up0 += __shfl_xor(up0, 16); up0 += __shfl_xor(up0, 32);
  up1 += __shfl_xor(up1, 16); up1 += __shfl_xor(up1, 32);
  if (l < 16) {
    const int n0 = 32 * w + l, n1 = n0 + 16;
    wlog[n0] = up0 * rsqrtf(fmaxf(r2s[n0], 1e-12f)) + bias[n0];
    wlog[n1] = up1 * rsqrtf(fmaxf(r2s[n1], 1e-12f)) + bias[n1];
  }
  __syncthreads();

  if (tid < 64) {
    const float a0 = wlog[tid], a1 = wlog[tid + 64], a2 = wlog[tid + 128], a3 = wlog[tid + 192];
    float mx = fmaxf(fmaxf(a0, a1), fmaxf(a2, a3));
    #pragma unroll
    for (int off = 32; off >= 1; off >>= 1) mx = fmaxf(mx, __shfl_xor(mx, off));
    const float e0 = __expf(a0 - mx), e1 = __expf(a1 - mx), e2 = __expf(a2 - mx), e3 = __expf(a3 - mx);
    float s = e0 + e1 + e2 + e3;
    #pragma unroll
    for (int off = 32; off >= 1; off >>= 1) s += __shfl_xor(s, off);
    const float inv = 1.0f / s;
    wexp[tid] = e0 * inv; wexp[tid + 64] = e1 * inv;
    wexp[tid + 128] = e2 * inv; wexp[tid + 192] = e3 * inv;
  }
  __syncthreads();

  if (tid < B_N) wexp_g[(size_t)b * B_N + tid] = wexp[tid];
}

// ---------------- Kernel 2: out = p[row] * x, pure streaming ---------------
// Grid-stride; 8 consecutive floats per thread per iter (one p per chunk,
// since 8-aligned chunks never straddle a 256-elem row).
__global__ __launch_bounds__(256, 8) void spat_mul(
    const float* __restrict__ x, const float* __restrict__ p,
    float* __restrict__ out, int nchunk)
{
  const int stride = gridDim.x * 256;
  for (int idx = blockIdx.x * 256 + threadIdx.x; idx < nchunk; idx += stride) {
    const int e = idx * 8;
    const float wt = p[e >> 8];             // global row = e / 256
    const float4 f0 = *reinterpret_cast<const float4*>(x + e);
    const float4 f1 = *reinterpret_cast<const float4*>(x + e + 4);
    f32x4 o0, o1;
    o0[0] = f0.x * wt; o0[1] = f0.y * wt; o0[2] = f0.z * wt; o0[3] = f0.w * wt;
    o1[0] = f1.x * wt; o1[1] = f1.y * wt; o1[2] = f1.z * wt; o1[3] = f1.w * wt;
    *reinterpret_cast<f32x4*>(out + e)     = o0;
    *reinterpret_cast<f32x4*>(out + e + 4) = o1;
  }
}

extern "C" void kernel_launch(void* const* d_in, const int* in_sizes, int n_in,
                              void* d_out, int out_size, void* d_ws, size_t ws_size,
                              hipStream_t stream) {
  const float* x    = (const float*)d_in[0];
  const float* kern = (const float*)d_in[1];
  const float* bias = (const float*)d_in[2];
  float* out = (float*)d_out;
  float* wexp_g = (float*)d_ws;                 // 512 KB scratch
  const int nb = in_sizes[0] / NELEM;           // 512 batches
  spat_attn_w<<<dim3(nb), dim3(512), 0, stream>>>(x, kern, bias, wexp_g);
  const int nchunk = nb * (NELEM / 8);          // 4,194,304 chunks of 8
  spat_mul<<<dim3(2048), dim3(256), 0, stream>>>(x, wexp_g, out, nchunk);
}